// Round 4
// baseline (463.612 us; speedup 1.0000x reference)
//
#include <hip/hip_runtime.h>

#define T_DIM 512
#define C_DIM 48
#define BPS   64          // bp row stride (padded to 64 so all lanes store)
#define CH    4           // global-prefetch chunk (distance ~4 steps)

#if __has_builtin(__builtin_amdgcn_readlane)
#define READLANE_I(v, l) __builtin_amdgcn_readlane((v), (l))
#else
#define READLANE_I(v, l) __shfl((v), (l), 64)
#endif

// Broadcast lane `lane`'s float to the whole wave (result is wave-uniform,
// lands in an SGPR). lane is a compile-time constant in all uses.
__device__ __forceinline__ float bcast_lane(float v, int lane) {
#if __has_builtin(__builtin_amdgcn_readlane)
    return __uint_as_float((unsigned)__builtin_amdgcn_readlane((int)__float_as_uint(v), lane));
#else
    float r;
    __asm__("v_readlane_b32 %0, %1, %2" : "=s"(r) : "v"(v), "i"(lane));
    return r;
#endif
}

// One Viterbi step. Scores live in sreg[48] (wave-uniform, SGPR-homed).
// Lane j computes argmax_i(sreg[i] + trans[i][j]) with exact lowest-i
// tie-break (4 contiguous chains, strict >, ordered merge), stores bp to LDS,
// then re-broadcasts the new score vector via readlane. No LDS on the
// score critical path -> no lgkmcnt stalls, full cross-step scheduling.
#define VSTEP(T_, PV_) do {                                                  \
    float v0 = sreg[0]  + tc[0];  int a0 = 0;                                \
    float v1 = sreg[12] + tc[12]; int a1 = 12;                               \
    float v2 = sreg[24] + tc[24]; int a2 = 24;                               \
    float v3 = sreg[36] + tc[36]; int a3 = 36;                               \
    _Pragma("unroll")                                                        \
    for (int c_ = 1; c_ < 12; ++c_) {                                        \
        float t0_ = sreg[c_]      + tc[c_];      if (t0_ > v0) { v0 = t0_; a0 = c_;      } \
        float t1_ = sreg[12 + c_] + tc[12 + c_]; if (t1_ > v1) { v1 = t1_; a1 = 12 + c_; } \
        float t2_ = sreg[24 + c_] + tc[24 + c_]; if (t2_ > v2) { v2 = t2_; a2 = 24 + c_; } \
        float t3_ = sreg[36 + c_] + tc[36 + c_]; if (t3_ > v3) { v3 = t3_; a3 = 36 + c_; } \
    }                                                                        \
    float vA = v0; int aA = a0;                                              \
    if (v1 > vA) { vA = v1; aA = a1; }                                       \
    float vB = v2; int aB = a2;                                              \
    if (v3 > vB) { vB = v3; aB = a3; }                                       \
    if (vB > vA) { vA = vB; aA = aB; }                                       \
    const float ns_ = vA + (PV_);                                            \
    bp[(T_) * BPS + tid] = (unsigned char)aA;  /* all 64 lanes; pad ok */    \
    _Pragma("unroll")                                                        \
    for (int i_ = 0; i_ < C_DIM; ++i_) sreg[i_] = bcast_lane(ns_, i_);       \
} while (0)

__global__ __launch_bounds__(64) void crf_viterbi(
    const float* __restrict__ pot,     // [B][T][C]
    const int*   __restrict__ seqlen,  // [B][1]
    const float* __restrict__ trans,   // [C][C]
    float*       __restrict__ out)     // [B][T][C] one-hot f32
{
    const int b   = blockIdx.x;
    const int tid = threadIdx.x;
    const int jj  = (tid < C_DIM) ? tid : (C_DIM - 1);  // clamped for safe loads

    __shared__ unsigned char bp[T_DIM * BPS];            // rows 1..L-1 used
    __shared__ __align__(4) unsigned char tags[T_DIM];

    const float* potb = pot + (size_t)b * (T_DIM * C_DIM);
    const int L   = seqlen[b];          // in [1, 511]
    const int thi = L - 1;

    // transitions column j in registers (clamped col for lanes >= 48)
    float tc[C_DIM];
#pragma unroll
    for (int i = 0; i < C_DIM; ++i) tc[i] = trans[i * C_DIM + jj];

    // init: score vector (wave-uniform) = potentials[:,0]
    float sreg[C_DIM];
    {
        const float s0 = potb[jj];
#pragma unroll
        for (int i = 0; i < C_DIM; ++i) sreg[i] = bcast_lane(s0, i);
    }

    const float* pp = potb + jj;

    // software-pipelined forward loop: prefetch chunk CH ahead (clamped rows)
    float pb[CH];
#pragma unroll
    for (int k = 0; k < CH; ++k) {
        int tt = 1 + k; if (tt > T_DIM - 1) tt = T_DIM - 1;
        pb[k] = pp[tt * C_DIM];
    }
    for (int t0 = 1; t0 < L; t0 += CH) {
        float nb[CH];
#pragma unroll
        for (int k = 0; k < CH; ++k) {
            int tt = t0 + CH + k; if (tt > T_DIM - 1) tt = T_DIM - 1;
            nb[k] = pp[tt * C_DIM];
        }
#pragma unroll
        for (int k = 0; k < CH; ++k) {
            const int t = t0 + k;
            if (t >= L) break;           // wave-uniform branch
            VSTEP(t, pb[k]);
        }
#pragma unroll
        for (int k = 0; k < CH; ++k) pb[k] = nb[k];
    }
    __syncthreads();   // phase boundary (single wave; cheap)

    // last_tag = argmax over final scores (wave-uniform values)
    float bv = sreg[0];
    int   bi = 0;
#pragma unroll
    for (int i = 1; i < C_DIM; ++i) {
        if (sreg[i] > bv) { bv = sreg[i]; bi = i; }
    }
    const int last_tag = __builtin_amdgcn_readfirstlane(bi);

    // prefill tags[t] = last_tag for t in [L, T)
    for (int t = L + tid; t < T_DIM; t += 64) tags[t] = (unsigned char)last_tag;

    // serial backtrace: for t = thi..1: tags[t] = y; y = bp[t][y];  then tags[0] = y
    int y = last_tag;  // wave-uniform
    for (int c0 = (thi >> 6) << 6; c0 >= 0; c0 -= 64) {
        int row[64];   // row[k] holds bp[c0+k][jj] in lane jj
#pragma unroll
        for (int k = 0; k < 64; ++k) row[k] = bp[(c0 + k) * BPS + jj];

        int vacc = 0;
#pragma unroll
        for (int k = 63; k >= 0; --k) {
            const int t = c0 + k;
            vacc = (tid == k) ? y : vacc;                        // tags[t] = y (lane k)
            const int ynew = READLANE_I(row[k], y);
            if ((unsigned)(t - 1) < (unsigned)thi) y = ynew;     // update only for t in [1, thi]
        }
        const int tk = c0 + tid;
        if (tk <= thi) tags[tk] = (unsigned char)(vacc & 0xff);
    }
    __syncthreads();   // phase boundary

    // emit one-hot: 4 rows (t) per iteration, 48 lanes x float4 = 768B coalesced
    if (tid < C_DIM) {
        const int r = tid / 12;          // row-in-group 0..3
        const int q = tid - r * 12;      // float4 slot 0..11
        const int cbase = q * 4;
        float* ob = out + (size_t)b * (T_DIM * C_DIM);
        for (int t0 = 0; t0 < T_DIM; t0 += 4) {
            const unsigned int tg4 = *(const unsigned int*)&tags[t0];
            const int mytag = (int)((tg4 >> (r * 8)) & 0xffu);
            float4 v;
            v.x = (cbase + 0 == mytag) ? 1.0f : 0.0f;
            v.y = (cbase + 1 == mytag) ? 1.0f : 0.0f;
            v.z = (cbase + 2 == mytag) ? 1.0f : 0.0f;
            v.w = (cbase + 3 == mytag) ? 1.0f : 0.0f;
            *(float4*)(ob + (size_t)(t0 + r) * C_DIM + cbase) = v;
        }
    }
}

extern "C" void kernel_launch(void* const* d_in, const int* in_sizes, int n_in,
                              void* d_out, int out_size, void* d_ws, size_t ws_size,
                              hipStream_t stream) {
    const float* pot    = (const float*)d_in[0];
    const int*   sl     = (const int*)d_in[1];
    const float* trans  = (const float*)d_in[2];
    float*       out    = (float*)d_out;
    const int B = in_sizes[1];  // sequence_lengths has B elements
    crf_viterbi<<<B, 64, 0, stream>>>(pot, sl, trans, out);
}